// Round 6
// baseline (165.930 us; speedup 1.0000x reference)
//
#include <hip/hip_runtime.h>

#define T_SEQ 2048
#define DHEAD 128
#define NBH 16
#define SCALE 0.08838834764831845f

typedef unsigned short u16;
typedef unsigned int u32;
typedef u16 u16x4 __attribute__((ext_vector_type(4)));
typedef u16 u16x8 __attribute__((ext_vector_type(8)));
typedef u32 u32x4 __attribute__((ext_vector_type(4)));
typedef __bf16 bf16x8 __attribute__((ext_vector_type(8)));
typedef float f32x16 __attribute__((ext_vector_type(16)));

__device__ __forceinline__ u16 f2bfu(float x) {
  union { float f; unsigned u; } c; c.f = x;
  unsigned u = c.u;
  u = u + 0x7FFFu + ((u >> 16) & 1u);   // RNE
  return (u16)(u >> 16);
}

__device__ __forceinline__ u32 packbf2(float lo, float hi) {
  return (u32)f2bfu(lo) | ((u32)f2bfu(hi) << 16);
}

__device__ __forceinline__ bf16x8 ldsFrag(const u16* p) {
  u16x8 t = *(const u16x8*)p;
  return __builtin_bit_cast(bf16x8, t);
}

__device__ __forceinline__ void gld_lds16(const void* g, void* l) {
  __builtin_amdgcn_global_load_lds(
      (__attribute__((address_space(1))) const unsigned int*)g,
      (__attribute__((address_space(3))) unsigned int*)l, 16, 0, 0);
}

// ---------------------------------------------------------------------------
// Gate scan: fc=cumsum(logsigmoid(f)); a=i-fc; c=cummax(a).
// ---------------------------------------------------------------------------
__global__ __launch_bounds__(256) void gate_scan_kernel(
    const float* __restrict__ ig, const float* __restrict__ fg,
    float* __restrict__ a_out, float* __restrict__ c_out,
    float* __restrict__ fc_out)
{
  const int bh  = blockIdx.x;
  const int tid = threadIdx.x;
  const int base = bh * T_SEQ + tid * 8;
  __shared__ float sbuf[256];

  float lf[8];
  float run = 0.f;
#pragma unroll
  for (int j = 0; j < 8; ++j) {
    float x  = fg[base + j];
    float ls = fminf(x, 0.f) - log1pf(expf(-fabsf(x)));
    run += ls; lf[j] = run;
  }
  sbuf[tid] = run; __syncthreads();
  for (int off = 1; off < 256; off <<= 1) {
    float t = (tid >= off) ? sbuf[tid - off] : 0.f;
    __syncthreads();
    sbuf[tid] += t;
    __syncthreads();
  }
  const float excl = (tid > 0) ? sbuf[tid - 1] : 0.f;
  __syncthreads();

  float fc[8], cm[8];
  float runm = -INFINITY;
#pragma unroll
  for (int j = 0; j < 8; ++j) {
    fc[j] = excl + lf[j];
    fc_out[base + j] = fc[j];
    float av = ig[base + j] - fc[j];
    a_out[base + j] = av;
    runm = fmaxf(runm, av);
    cm[j] = runm;
  }
  sbuf[tid] = runm; __syncthreads();
  for (int off = 1; off < 256; off <<= 1) {
    float t = (tid >= off) ? sbuf[tid - off] : -INFINITY;
    __syncthreads();
    sbuf[tid] = fmaxf(sbuf[tid], t);
    __syncthreads();
  }
  const float exclm = (tid > 0) ? sbuf[tid - 1] : -INFINITY;
#pragma unroll
  for (int j = 0; j < 8; ++j) {
    c_out[base + j] = fmaxf(exclm, cm[j]);
  }
}

// ---------------------------------------------------------------------------
// Pre-pass: K_hat = K * exp(a[s] - c_tile_end(s)), fp32 -> bf16.
// ---------------------------------------------------------------------------
__global__ __launch_bounds__(256) void cvt_k_kernel(
    const float* __restrict__ src, const float* __restrict__ ag,
    const float* __restrict__ cg, u16* __restrict__ dst)
{
  const int i = (blockIdx.x * 256 + threadIdx.x) * 4;
  const int bhs = i >> 7;                         // [bh][s] combined index
  const float sc = __expf(ag[bhs] - cg[bhs | 63]);  // <= 1 (cummax >= a)
  const float4 x = *(const float4*)(src + i);
  u16x4 p;
  p[0] = f2bfu(x.x * sc); p[1] = f2bfu(x.y * sc);
  p[2] = f2bfu(x.z * sc); p[3] = f2bfu(x.w * sc);
  *(u16x4*)(dst + i) = p;
}

// ---------------------------------------------------------------------------
// Pre-pass: V fp32 [bh][key][n] -> bf16 transposed Vt [bh][n][key].
// ---------------------------------------------------------------------------
__global__ __launch_bounds__(256) void cvt_vt_kernel(
    const float* __restrict__ v, u16* __restrict__ vt)
{
  const int bh = blockIdx.y, kt = blockIdx.x, tid = threadIdx.x;
  __shared__ __align__(16) u16 L[128 * 72];
  const int n0 = (tid & 31) * 4, k0 = (tid >> 5) * 8;
  const float* vp = v + ((size_t)bh * T_SEQ + kt * 64 + k0) * DHEAD + n0;
  u16 tv[4][8];
#pragma unroll
  for (int rr = 0; rr < 8; ++rr) {
    const float4 x = *(const float4*)(vp + rr * DHEAD);
    tv[0][rr] = f2bfu(x.x); tv[1][rr] = f2bfu(x.y);
    tv[2][rr] = f2bfu(x.z); tv[3][rr] = f2bfu(x.w);
  }
#pragma unroll
  for (int j = 0; j < 4; ++j) {
    u16x8 p;
#pragma unroll
    for (int rr = 0; rr < 8; ++rr) p[rr] = tv[j][rr];
    *(u16x8*)(&L[(n0 + j) * 72 + k0]) = p;
  }
  __syncthreads();
  const int row = tid >> 1, s0 = (tid & 1) * 32;
  u16* op = vt + ((size_t)bh * DHEAD + row) * T_SEQ + kt * 64 + s0;
#pragma unroll
  for (int i = 0; i < 4; ++i)
    *(u16x8*)(op + i * 8) = *(const u16x8*)(&L[row * 72 + s0 + i * 8]);
}

// ---------------------------------------------------------------------------
// Main flash mLSTM.  256 blocks x 512 thr.  Transposed formulation:
//   S^T = K_hat * Q^T  (C/D col = lane = q-row -> B-frag-ready for PV)
//   O^T = V^T * P^T    (P^T from S^T regs via 4x shfl_xor(32), no LDS)
// Waves: qsel(2) x key-half(2) x strip(2); pairing (31-p, p) -> uniform work.
// LDS: 64KB K/V dbuf staging only.  Per-iter: 1 expf, 8+8 MFMA, 16 b128.
// ---------------------------------------------------------------------------
template <bool FAST>
__global__ __launch_bounds__(512, 1) void mlstm_fwd_kernel(
    const float* __restrict__ qg, const float* __restrict__ kg,
    const float* __restrict__ vg,
    const u16* __restrict__ kbf, const u16* __restrict__ vtbf,
    const float* __restrict__ ag, const float* __restrict__ cg,
    const float* __restrict__ fcg, float* __restrict__ out)
{
  const int bx = (int)blockIdx.x;
  const int bh = bx & 15, p = bx >> 4;
  const int tid = (int)threadIdx.x;
  const int w8 = tid >> 6, lane = tid & 63;
  const int hh = lane >> 5, l32 = lane & 31;

  const int qsel  = w8 >> 2;
  const int half  = (w8 >> 1) & 1;
  const int strip = w8 & 1;
  const int qt    = qsel ? p : (31 - p);
  const int nST   = 32 - p;
  const int qrow0 = qt * 64 + strip * 32;
  const int qrowg = qrow0 + l32;                 // this lane's q-row

  __shared__ __align__(16) unsigned char SM[65536];  // dbuf: K 16K + V 16K each
  __shared__ float rsh[128];

  const size_t hoff = (size_t)bh * T_SEQ * DHEAD;
  const int goff = bh * T_SEQ;

  // Q -> B-frags (n = lane = q-row, k = d-chunk)
  bf16x8 qf[8];
  {
    const float* qp = qg + hoff + (size_t)qrowg * DHEAD + hh * 8;
#pragma unroll
    for (int ks = 0; ks < 8; ++ks) {
      const float4 x0 = *(const float4*)(qp + ks * 16);
      const float4 x1 = *(const float4*)(qp + ks * 16 + 4);
      u16x8 t;
      t[0] = f2bfu(x0.x); t[1] = f2bfu(x0.y); t[2] = f2bfu(x0.z); t[3] = f2bfu(x0.w);
      t[4] = f2bfu(x1.x); t[5] = f2bfu(x1.y); t[6] = f2bfu(x1.z); t[7] = f2bfu(x1.w);
      qf[ks] = __builtin_bit_cast(bf16x8, t);
    }
  }
  const float cmax = cg[goff + qt * 64 + 63];

  f32x16 oa[4];
#pragma unroll
  for (int nt = 0; nt < 4; ++nt)
#pragma unroll
    for (int r = 0; r < 16; ++r) oa[nt][r] = 0.f;
  float rsacc = 0.f;

  float kr[2][8], vr[2][8];   // fallback staging regs

  auto stage_issue = [&](int st, int b) {
    if (FAST) {
      const u16* ks = kbf + ((size_t)goff + st * 64) * DHEAD;
      const u16* vs = vtbf + (size_t)bh * DHEAD * T_SEQ + st * 64;
#pragma unroll
      for (int j = 0; j < 2; ++j) {
        const int B = (w8 * 2 + j) * 64 + lane;
        {
          const int key = B >> 4;
          const int db = (B & 15) ^ (key & 7);
          gld_lds16(ks + (size_t)key * DHEAD + db * 8,
                    (u16*)(SM + b * 32768) + (w8 * 2 + j) * 512);
        }
        {
          const int n = B >> 3;
          const int kb = (B & 7) ^ (n & 7);
          gld_lds16(vs + (size_t)n * T_SEQ + kb * 8,
                    (u16*)(SM + b * 32768 + 16384) + (w8 * 2 + j) * 512);
        }
      }
    } else {
      const float ct = cg[goff + st * 64 + 63];
      const float* kp = kg + hoff + (size_t)(st * 64) * DHEAD;
      const float* vp = vg + hoff + (size_t)(st * 64) * DHEAD;
#pragma unroll
      for (int j = 0; j < 2; ++j) {
        const int B = (w8 * 2 + j) * 64 + lane;
        const int key = B >> 4;
        const int db = (B & 15) ^ (key & 7);
        const float sc = __expf(ag[goff + st * 64 + key] - ct);
        const float4 x0 = *(const float4*)(kp + (size_t)key * DHEAD + db * 8);
        const float4 x1 = *(const float4*)(kp + (size_t)key * DHEAD + db * 8 + 4);
        kr[j][0] = x0.x * sc; kr[j][1] = x0.y * sc; kr[j][2] = x0.z * sc; kr[j][3] = x0.w * sc;
        kr[j][4] = x1.x * sc; kr[j][5] = x1.y * sc; kr[j][6] = x1.z * sc; kr[j][7] = x1.w * sc;
        const int n = B >> 3;
        const int kb = (B & 7) ^ (n & 7);
#pragma unroll
        for (int rr = 0; rr < 8; ++rr)
          vr[j][rr] = vp[(size_t)(kb * 8 + rr) * DHEAD + n];
      }
    }
  };
  auto stage_commit = [&](int b) {
    if (!FAST) {
#pragma unroll
      for (int j = 0; j < 2; ++j) {
        const int B = (w8 * 2 + j) * 64 + lane;
        u16x8 pk, pw;
#pragma unroll
        for (int rr = 0; rr < 8; ++rr) { pk[rr] = f2bfu(kr[j][rr]); pw[rr] = f2bfu(vr[j][rr]); }
        *(u16x8*)((u16*)(SM + b * 32768) + B * 8) = pk;
        *(u16x8*)((u16*)(SM + b * 32768 + 16384) + B * 8) = pw;
      }
    }
  };

  stage_issue(0, 0);
  stage_commit(0);
  __syncthreads();

  for (int st = 0; st < nST; ++st) {
    const int b = st & 1;
    if (st + 1 < nST) stage_issue(st + 1, b ^ 1);

    const bool act = (qsel == 0) || (st <= qt);
    if (act) {
      const u16* Kb_ = (const u16*)(SM + b * 32768);
      const u16* Vb_ = (const u16*)(SM + b * 32768 + 16384);
      const int keyl = half * 32 + l32;          // wave's key (A-frag m)

      // ---- S^T = K_hat Q^T, two 4-deep chains ----
      f32x16 s0, s1;
#pragma unroll
      for (int r = 0; r < 16; ++r) { s0[r] = 0.f; s1[r] = 0.f; }
#pragma unroll
      for (int k2 = 0; k2 < 4; ++k2) {
        {
          const int db = 2 * (2 * k2) + hh;
          const bf16x8 kf = ldsFrag(Kb_ + keyl * 128 + ((db ^ (keyl & 7)) * 8));
          s0 = __builtin_amdgcn_mfma_f32_32x32x16_bf16(kf, qf[2 * k2], s0, 0, 0, 0);
        }
        {
          const int db = 2 * (2 * k2 + 1) + hh;
          const bf16x8 kf = ldsFrag(Kb_ + keyl * 128 + ((db ^ (keyl & 7)) * 8));
          s1 = __builtin_amdgcn_mfma_f32_32x32x16_bf16(kf, qf[2 * k2 + 1], s1, 0, 0, 0);
        }
      }
      const float etile = SCALE * __expf(cg[goff + st * 64 + 63] - cmax);
      const bool diag = (st == qt);

      float pv[16];
      float r0 = 0.f, r1 = 0.f, r2 = 0.f, r3 = 0.f;
#pragma unroll
      for (int reg = 0; reg < 16; ++reg) {
        float x = (s0[reg] + s1[reg]) * etile;
        if (diag) {
          const int rowl = (reg & 3) + 8 * (reg >> 2) + 4 * hh;
          if (st * 64 + half * 32 + rowl > qrowg) x = 0.f;
        }
        pv[reg] = x;
        if ((reg & 3) == 0) r0 += x; else if ((reg & 3) == 1) r1 += x;
        else if ((reg & 3) == 2) r2 += x; else r3 += x;
      }
      rsacc += (r0 + r1) + (r2 + r3);

      u32 d8[8];
#pragma unroll
      for (int q = 0; q < 4; ++q) {
        d8[2 * q]     = packbf2(pv[4 * q],     pv[4 * q + 1]);
        d8[2 * q + 1] = packbf2(pv[4 * q + 2], pv[4 * q + 3]);
      }
      // ---- O^T += V^T P^T ----
#pragma unroll
      for (int k2 = 0; k2 < 2; ++k2) {
        const int qo = 2 * k2 + (hh ^ 1), qn = 2 * k2 + hh;
        const u32 e0 = __shfl_xor(d8[2 * qo], 32, 64);
        const u32 e1 = __shfl_xor(d8[2 * qo + 1], 32, 64);
        const u32x4 fw = hh ? (u32x4){e0, e1, d8[2 * qn], d8[2 * qn + 1]}
                            : (u32x4){d8[2 * qn], d8[2 * qn + 1], e0, e1};
        const bf16x8 pfrag = __builtin_bit_cast(bf16x8, fw);
        const int kb = half * 4 + k2 * 2 + hh;
#pragma unroll
        for (int nt = 0; nt < 4; ++nt) {
          const int n = nt * 32 + l32;
          const bf16x8 vf = ldsFrag(Vb_ + n * 64 + ((kb ^ (n & 7)) * 8));
          oa[nt] = __builtin_amdgcn_mfma_f32_32x32x16_bf16(vf, pfrag, oa[nt], 0, 0, 0);
        }
      }
    }
    if (st + 1 < nST) stage_commit(b ^ 1);
    __syncthreads();
  }

  // ---- epilogue: combine key-halves, normalize, store O (from O^T) ----
  rsacc += __shfl_xor(rsacc, 32, 64);
  const int combo = qsel * 2 + strip;
  float* osh = (float*)SM;                       // 4 combos x 128n x 32row f32

  if (half == 1) {
#pragma unroll
    for (int nt = 0; nt < 4; ++nt)
#pragma unroll
      for (int reg = 0; reg < 16; ++reg) {
        const int rown = (reg & 3) + 8 * (reg >> 2) + 4 * hh;
        osh[combo * 4096 + (nt * 32 + rown) * 32 + l32] = oa[nt][reg];
      }
    if (hh == 0) rsh[combo * 32 + l32] = rsacc;
  }
  __syncthreads();
  if (half == 0) {
    const float rstot = rsacc + rsh[combo * 32 + l32];
    const float nf = __expf(-(cmax + fcg[goff + qrowg]));
    const float inv = 1.f / fmaxf(fabsf(rstot), nf);
    float* op = out + hoff + (size_t)qrowg * DHEAD;
#pragma unroll
    for (int nt = 0; nt < 4; ++nt)
#pragma unroll
      for (int q = 0; q < 4; ++q) {
        float4 ov;
        const int base = combo * 4096 + (nt * 32 + 8 * q + 4 * hh) * 32 + l32;
        ov.x = (oa[nt][4 * q]     + osh[base])      * inv;
        ov.y = (oa[nt][4 * q + 1] + osh[base + 32]) * inv;
        ov.z = (oa[nt][4 * q + 2] + osh[base + 64]) * inv;
        ov.w = (oa[nt][4 * q + 3] + osh[base + 96]) * inv;
        *(float4*)(op + nt * 32 + 8 * q + 4 * hh) = ov;
      }
  }
}

// ---------------------------------------------------------------------------
extern "C" void kernel_launch(void* const* d_in, const int* in_sizes, int n_in,
                              void* d_out, int out_size, void* d_ws, size_t ws_size,
                              hipStream_t stream) {
  const float* q  = (const float*)d_in[0];
  const float* k  = (const float*)d_in[1];
  const float* v  = (const float*)d_in[2];
  const float* ig = (const float*)d_in[3];
  const float* fg = (const float*)d_in[4];

  const size_t gate_bytes = (size_t)3 * NBH * T_SEQ * sizeof(float);
  const size_t kv_elems   = (size_t)NBH * T_SEQ * DHEAD;
  const bool fast = ws_size >= gate_bytes + 2 * kv_elems * sizeof(u16);

  float* a_ws  = (float*)d_ws;
  float* c_ws  = a_ws + NBH * T_SEQ;
  float* fc_ws = c_ws + NBH * T_SEQ;
  u16* kbf  = (u16*)((char*)d_ws + gate_bytes);
  u16* vtbf = kbf + kv_elems;

  gate_scan_kernel<<<dim3(NBH), dim3(256), 0, stream>>>(ig, fg, a_ws, c_ws, fc_ws);
  if (fast) {
    cvt_k_kernel<<<dim3((unsigned)(kv_elems / 1024)), dim3(256), 0, stream>>>(
        k, a_ws, c_ws, kbf);
    cvt_vt_kernel<<<dim3(T_SEQ / 64, NBH), dim3(256), 0, stream>>>(v, vtbf);
    mlstm_fwd_kernel<true><<<dim3(256), dim3(512), 0, stream>>>(
        q, k, v, kbf, vtbf, a_ws, c_ws, fc_ws, (float*)d_out);
  } else {
    mlstm_fwd_kernel<false><<<dim3(256), dim3(512), 0, stream>>>(
        q, k, v, kbf, vtbf, a_ws, c_ws, fc_ws, (float*)d_out);
  }
}

// Round 8
// 150.273 us; speedup vs baseline: 1.1042x; 1.1042x over previous
//
#include <hip/hip_runtime.h>

#define T_SEQ 2048
#define DHEAD 128
#define NBH 16
#define SCALE 0.08838834764831845f

typedef unsigned short u16;
typedef unsigned int u32;
typedef u16 u16x4 __attribute__((ext_vector_type(4)));
typedef u16 u16x8 __attribute__((ext_vector_type(8)));
typedef u32 u32x2 __attribute__((ext_vector_type(2)));
typedef short s16x4 __attribute__((ext_vector_type(4)));
typedef __bf16 bf16x8 __attribute__((ext_vector_type(8)));
typedef float f32x4 __attribute__((ext_vector_type(4)));

__device__ __forceinline__ u16 f2bfu(float x) {
  union { float f; unsigned u; } c; c.f = x;
  unsigned u = c.u;
  u = u + 0x7FFFu + ((u >> 16) & 1u);   // RNE
  return (u16)(u >> 16);
}

__device__ __forceinline__ u32 packbf2(float lo, float hi) {
  return (u32)f2bfu(lo) | ((u32)f2bfu(hi) << 16);
}

__device__ __forceinline__ bf16x8 ldsFrag(const u16* p) {
  u16x8 t = *(const u16x8*)p;
  return __builtin_bit_cast(bf16x8, t);
}

__device__ __forceinline__ f32x4 mfma16x16x16bf16(s16x4 a, s16x4 b, f32x4 c) {
#if __has_builtin(__builtin_amdgcn_mfma_f32_16x16x16bf16_1k)
  return __builtin_amdgcn_mfma_f32_16x16x16bf16_1k(a, b, c, 0, 0, 0);
#else
  asm("v_mfma_f32_16x16x16_bf16 %0, %1, %2, %0" : "+v"(c) : "v"(a), "v"(b));
  return c;
#endif
}

__device__ __forceinline__ void gld_lds16(const void* g, void* l) {
  __builtin_amdgcn_global_load_lds(
      (__attribute__((address_space(1))) const unsigned int*)g,
      (__attribute__((address_space(3))) unsigned int*)l, 16, 0, 0);
}

// ---------------------------------------------------------------------------
// Gate scan: fc=cumsum(logsigmoid(f)); a=i-fc; c=cummax(a).
// ---------------------------------------------------------------------------
__global__ __launch_bounds__(256) void gate_scan_kernel(
    const float* __restrict__ ig, const float* __restrict__ fg,
    float* __restrict__ a_out, float* __restrict__ c_out,
    float* __restrict__ fc_out)
{
  const int bh  = blockIdx.x;
  const int tid = threadIdx.x;
  const int base = bh * T_SEQ + tid * 8;
  __shared__ float sbuf[256];

  float lf[8];
  float run = 0.f;
#pragma unroll
  for (int j = 0; j < 8; ++j) {
    float x  = fg[base + j];
    float ls = fminf(x, 0.f) - log1pf(expf(-fabsf(x)));
    run += ls; lf[j] = run;
  }
  sbuf[tid] = run; __syncthreads();
  for (int off = 1; off < 256; off <<= 1) {
    float t = (tid >= off) ? sbuf[tid - off] : 0.f;
    __syncthreads();
    sbuf[tid] += t;
    __syncthreads();
  }
  const float excl = (tid > 0) ? sbuf[tid - 1] : 0.f;
  __syncthreads();

  float fc[8], cm[8];
  float runm = -INFINITY;
#pragma unroll
  for (int j = 0; j < 8; ++j) {
    fc[j] = excl + lf[j];
    fc_out[base + j] = fc[j];
    float av = ig[base + j] - fc[j];
    a_out[base + j] = av;
    runm = fmaxf(runm, av);
    cm[j] = runm;
  }
  sbuf[tid] = runm; __syncthreads();
  for (int off = 1; off < 256; off <<= 1) {
    float t = (tid >= off) ? sbuf[tid - off] : -INFINITY;
    __syncthreads();
    sbuf[tid] = fmaxf(sbuf[tid], t);
    __syncthreads();
  }
  const float exclm = (tid > 0) ? sbuf[tid - 1] : -INFINITY;
#pragma unroll
  for (int j = 0; j < 8; ++j) {
    c_out[base + j] = fmaxf(exclm, cm[j]);
  }
}

// ---------------------------------------------------------------------------
// Pre-pass: K_hat = K * exp(a[s] - c_tile_end(s)), fp32 -> bf16.
// ---------------------------------------------------------------------------
__global__ __launch_bounds__(256) void cvt_k_kernel(
    const float* __restrict__ src, const float* __restrict__ ag,
    const float* __restrict__ cg, u16* __restrict__ dst)
{
  const int i = (blockIdx.x * 256 + threadIdx.x) * 4;
  const int bhs = i >> 7;
  const float sc = __expf(ag[bhs] - cg[bhs | 63]);  // <= 1
  const float4 x = *(const float4*)(src + i);
  u16x4 p;
  p[0] = f2bfu(x.x * sc); p[1] = f2bfu(x.y * sc);
  p[2] = f2bfu(x.z * sc); p[3] = f2bfu(x.w * sc);
  *(u16x4*)(dst + i) = p;
}

// ---------------------------------------------------------------------------
// Pre-pass: V fp32 [bh][key][n] -> bf16 transposed Vt [bh][n][key].
// ---------------------------------------------------------------------------
__global__ __launch_bounds__(256) void cvt_vt_kernel(
    const float* __restrict__ v, u16* __restrict__ vt)
{
  const int bh = blockIdx.y, kt = blockIdx.x, tid = threadIdx.x;
  __shared__ __align__(16) u16 L[128 * 72];
  const int n0 = (tid & 31) * 4, k0 = (tid >> 5) * 8;
  const float* vp = v + ((size_t)bh * T_SEQ + kt * 64 + k0) * DHEAD + n0;
  u16 tv[4][8];
#pragma unroll
  for (int rr = 0; rr < 8; ++rr) {
    const float4 x = *(const float4*)(vp + rr * DHEAD);
    tv[0][rr] = f2bfu(x.x); tv[1][rr] = f2bfu(x.y);
    tv[2][rr] = f2bfu(x.z); tv[3][rr] = f2bfu(x.w);
  }
#pragma unroll
  for (int j = 0; j < 4; ++j) {
    u16x8 p;
#pragma unroll
    for (int rr = 0; rr < 8; ++rr) p[rr] = tv[j][rr];
    *(u16x8*)(&L[(n0 + j) * 72 + k0]) = p;
  }
  __syncthreads();
  const int row = tid >> 1, s0 = (tid & 1) * 32;
  u16* op = vt + ((size_t)bh * DHEAD + row) * T_SEQ + kt * 64 + s0;
#pragma unroll
  for (int i = 0; i < 4; ++i)
    *(u16x8*)(op + i * 8) = *(const u16x8*)(&L[row * 72 + s0 + i * 8]);
}

// ---------------------------------------------------------------------------
// Main flash mLSTM.  256 blocks x 512 thr (8 waves).  Pair (31-p, p).
// 4 waves per q-tile, KEY-SPLIT 4: wave kg owns 16 keys x all 64 q-rows.
//   S^T = K_hat Q^T (16x16x32): A=K from LDS (4 b128/iter), B=Q in regs.
//   C-layout of S^T (col=qrow, row=key: lane holds 4 consecutive keys)
//   == B-operand of mfma_f32_16x16x16_bf16  ->  P stays in REGISTERS.
//   O^T += V^T P^T (16x16x16): A=V b64 reads (8/iter), partial over 16 keys.
// One barrier/iter; dbuf async staging; partial-O combined via LDS epilogue.
// LDS/wave/iter = 8 KB (vs 18+ before) -> LDS pipe no longer 5x oversubscribed.
// ---------------------------------------------------------------------------
template <bool FAST>
__global__ __launch_bounds__(512, 1) void mlstm_fwd_kernel(
    const float* __restrict__ qg, const float* __restrict__ kxg,
    const float* __restrict__ vg,
    const u16* __restrict__ kbf, const u16* __restrict__ vtbf,
    const float* __restrict__ ag, const float* __restrict__ cg,
    const float* __restrict__ fcg, float* __restrict__ out)
{
  const int bx = (int)blockIdx.x;
  const int bh = bx & 15, p = bx >> 4;
  const int tid = (int)threadIdx.x;
  const int w8 = tid >> 6, lane = tid & 63;
  const int quad = lane >> 4, l16 = lane & 15;

  const int qsel = w8 >> 2;            // 0: tile 31-p, 1: tile p
  const int kg4  = w8 & 3;             // key-group (16 keys each)
  const int qt   = qsel ? p : (31 - p);
  const int nST  = 32 - p;
  const int qrow0 = qt * 64;

  // LDS: K dbuf 2x16K @0, V dbuf 2x16K @32768 (loop phase);
  // epilogue: osh 2x64x129 f32 @0 (66048 B), rsh @66048 (2x4x64 f32).
  __shared__ __align__(16) unsigned char SM[68096];

  const size_t hoff = (size_t)bh * T_SEQ * DHEAD;
  const int goff = bh * T_SEQ;

  // Q -> B-frags qf[nt*4+kc]: B[k=quad*8+j][n=l16], n = qrow nt*16+l16
  bf16x8 qf[16];
#pragma unroll
  for (int nt = 0; nt < 4; ++nt) {
    const float* qp = qg + hoff + (size_t)(qrow0 + nt * 16 + l16) * DHEAD + quad * 8;
#pragma unroll
    for (int kc = 0; kc < 4; ++kc) {
      const float4 x0 = *(const float4*)(qp + kc * 32);
      const float4 x1 = *(const float4*)(qp + kc * 32 + 4);
      u16x8 t;
      t[0] = f2bfu(x0.x); t[1] = f2bfu(x0.y); t[2] = f2bfu(x0.z); t[3] = f2bfu(x0.w);
      t[4] = f2bfu(x1.x); t[5] = f2bfu(x1.y); t[6] = f2bfu(x1.z); t[7] = f2bfu(x1.w);
      qf[nt * 4 + kc] = __builtin_bit_cast(bf16x8, t);
    }
  }
  const float cmax = cg[goff + qt * 64 + 63];

  f32x4 oa[8][4];                      // O^T partial: 8 vd-tiles x 4 qrow-tiles
#pragma unroll
  for (int mt = 0; mt < 8; ++mt)
#pragma unroll
    for (int nt = 0; nt < 4; ++nt) oa[mt][nt] = (f32x4){0.f, 0.f, 0.f, 0.f};
  float rsacc[4] = {0.f, 0.f, 0.f, 0.f};

  auto stage = [&](int st) {
    const int b = st & 1;
    u16* KbL = (u16*)(SM + b * 16384);
    u16* VbL = (u16*)(SM + 32768 + b * 16384);
    if (FAST) {
      const u16* ks = kbf + ((size_t)goff + st * 64) * DHEAD;
      const u16* vs = vtbf + (size_t)bh * DHEAD * T_SEQ + st * 64;
#pragma unroll
      for (int j = 0; j < 2; ++j) {
        const int B = (w8 * 2 + j) * 64 + lane;
        { const int key = B >> 4; const int db = (B & 15) ^ (key & 7);
          gld_lds16(ks + (size_t)key * DHEAD + db * 8, KbL + (w8 * 2 + j) * 512); }
        { const int n = B >> 3; const int kb = (B & 7) ^ (n & 7);
          gld_lds16(vs + (size_t)n * T_SEQ + kb * 8, VbL + (w8 * 2 + j) * 512); }
      }
    } else {
      const float ct = cg[goff + st * 64 + 63];
      const float* kp = kxg + hoff + (size_t)(st * 64) * DHEAD;
      const float* vp = vg + hoff + (size_t)(st * 64) * DHEAD;
#pragma unroll
      for (int j = 0; j < 2; ++j) {
        const int B = (w8 * 2 + j) * 64 + lane;
        { const int key = B >> 4; const int db = (B & 15) ^ (key & 7);
          const float sc = __expf(ag[goff + st * 64 + key] - ct);
          const float4 x0 = *(const float4*)(kp + (size_t)key * DHEAD + db * 8);
          const float4 x1 = *(const float4*)(kp + (size_t)key * DHEAD + db * 8 + 4);
          u16x8 pk;
          pk[0] = f2bfu(x0.x * sc); pk[1] = f2bfu(x0.y * sc);
          pk[2] = f2bfu(x0.z * sc); pk[3] = f2bfu(x0.w * sc);
          pk[4] = f2bfu(x1.x * sc); pk[5] = f2bfu(x1.y * sc);
          pk[6] = f2bfu(x1.z * sc); pk[7] = f2bfu(x1.w * sc);
          *(u16x8*)(KbL + B * 8) = pk; }
        { const int n = B >> 3; const int kb = (B & 7) ^ (n & 7);
          u16x8 pw;
#pragma unroll
          for (int rr = 0; rr < 8; ++rr)
            pw[rr] = f2bfu(vp[(size_t)(kb * 8 + rr) * DHEAD + n]);
          *(u16x8*)(VbL + B * 8) = pw; }
      }
    }
  };

  stage(0);
  __syncthreads();

  const int keyA = kg4 * 16 + l16;     // A-frag key row (QK)
  const int ksw  = l16 & 7;
  const int kbu  = kg4 * 2 + (quad >> 1);   // V unit base (PV)
  const int kofs = (quad & 1) * 4;

  for (int st = 0; st < nST; ++st) {
    const int b = st & 1;
    if (st + 1 < nST) stage(st + 1);

    if (st <= qt) {
      const u16* KbL = (const u16*)(SM + b * 16384);
      const u16* VbL = (const u16*)(SM + 32768 + b * 16384);

      // ---- S^T = K_hat Q^T ----
      f32x4 sa[4];
#pragma unroll
      for (int nt = 0; nt < 4; ++nt) sa[nt] = (f32x4){0.f, 0.f, 0.f, 0.f};
#pragma unroll
      for (int kc = 0; kc < 4; ++kc) {
        const bf16x8 kf = ldsFrag(KbL + keyA * 128 + (((kc * 4 + quad) ^ ksw) * 8));
        sa[0] = __builtin_amdgcn_mfma_f32_16x16x32_bf16(kf, qf[0 * 4 + kc], sa[0], 0, 0, 0);
        sa[1] = __builtin_amdgcn_mfma_f32_16x16x32_bf16(kf, qf[1 * 4 + kc], sa[1], 0, 0, 0);
        sa[2] = __builtin_amdgcn_mfma_f32_16x16x32_bf16(kf, qf[2 * 4 + kc], sa[2], 0, 0, 0);
        sa[3] = __builtin_amdgcn_mfma_f32_16x16x32_bf16(kf, qf[3 * 4 + kc], sa[3], 0, 0, 0);
      }

      const float etile = SCALE * __expf(cg[goff + st * 64 + 63] - cmax);
      const bool diag = (st == qt);

      // ---- P^T in registers (B-frags of 16x16x16) ----
      s16x4 pfr[4];
#pragma unroll
      for (int nt = 0; nt < 4; ++nt) {
        float x0 = sa[nt][0] * etile, x1 = sa[nt][1] * etile;
        float x2 = sa[nt][2] * etile, x3 = sa[nt][3] * etile;
        if (diag) {
          const int qr = nt * 16 + l16, kb0 = kg4 * 16 + quad * 4;
          if (kb0 + 0 > qr) x0 = 0.f;
          if (kb0 + 1 > qr) x1 = 0.f;
          if (kb0 + 2 > qr) x2 = 0.f;
          if (kb0 + 3 > qr) x3 = 0.f;
        }
        rsacc[nt] += (x0 + x1) + (x2 + x3);
        pfr[nt] = __builtin_bit_cast(s16x4, (u32x2){packbf2(x0, x1), packbf2(x2, x3)});
      }

      // ---- O^T += V^T P^T ----
#pragma unroll
      for (int mt = 0; mt < 8; ++mt) {
        const int vd = mt * 16 + l16;
        const s16x4 va = *(const s16x4*)(VbL + vd * 64 + ((kbu ^ (vd & 7)) * 8) + kofs);
        oa[mt][0] = mfma16x16x16bf16(va, pfr[0], oa[mt][0]);
        oa[mt][1] = mfma16x16x16bf16(va, pfr[1], oa[mt][1]);
        oa[mt][2] = mfma16x16x16bf16(va, pfr[2], oa[mt][2]);
        oa[mt][3] = mfma16x16x16bf16(va, pfr[3], oa[mt][3]);
      }
    }
    __syncthreads();
  }

  // ---- epilogue 1: rowsum combine ----
  float rst[4];
#pragma unroll
  for (int nt = 0; nt < 4; ++nt) {
    float x = rsacc[nt];
    x += __shfl_xor(x, 16, 64);
    x += __shfl_xor(x, 32, 64);
    rst[nt] = x;
  }
  float* rshp = (float*)(SM + 66048);
  if (lane < 16) {
#pragma unroll
    for (int nt = 0; nt < 4; ++nt)
      rshp[qsel * 256 + kg4 * 64 + nt * 16 + lane] = rst[nt];
  }
  __syncthreads();

  float inv[4] = {0.f, 0.f, 0.f, 0.f};
  if (kg4 == 3) {
#pragma unroll
    for (int nt = 0; nt < 4; ++nt) {
      const int row = nt * 16 + l16;
      const float tot = rshp[qsel * 256 + row] + rshp[qsel * 256 + 64 + row]
                      + rshp[qsel * 256 + 128 + row] + rshp[qsel * 256 + 192 + row];
      const float nf = __expf(-(cmax + fcg[goff + qrow0 + row]));
      inv[nt] = 1.f / fmaxf(fabsf(tot), nf);
    }
  }

  // ---- epilogue 2: 4-round partial-O combine into osh[tile][row][vd] ----
  float* osh = (float*)SM;
  const int obase = qsel * 64 * 129;
  for (int r = 0; r < 4; ++r) {
    if (kg4 == r) {
#pragma unroll
      for (int mt = 0; mt < 8; ++mt)
#pragma unroll
        for (int nt = 0; nt < 4; ++nt)
#pragma unroll
          for (int rg = 0; rg < 4; ++rg) {
            const int row = nt * 16 + l16;
            const int vd = mt * 16 + quad * 4 + rg;
            const int ad = obase + row * 129 + vd;
            float v = oa[mt][nt][rg];
            if (r > 0) v += osh[ad];
            if (r == 3) v *= inv[nt];
            osh[ad] = v;
          }
    }
    __syncthreads();
  }

  // ---- epilogue 3: cooperative coalesced store ----
  {
    const int col = tid & 31;           // float4 column
    const int rg0 = tid >> 5;           // 0..15
#pragma unroll
    for (int i = 0; i < 8; ++i) {
      const int ra = rg0 + 16 * i;      // 0..127
      const int tile = ra >> 6, row = ra & 63;
      const int qtt = tile ? p : (31 - p);
      const float* lp = osh + (tile * 64 + row) * 129 + col * 4;
      float4 v; v.x = lp[0]; v.y = lp[1]; v.z = lp[2]; v.w = lp[3];
      *(float4*)(out + hoff + (size_t)(qtt * 64 + row) * DHEAD + col * 4) = v;
    }
  }
}

// ---------------------------------------------------------------------------
extern "C" void kernel_launch(void* const* d_in, const int* in_sizes, int n_in,
                              void* d_out, int out_size, void* d_ws, size_t ws_size,
                              hipStream_t stream) {
  const float* q  = (const float*)d_in[0];
  const float* k  = (const float*)d_in[1];
  const float* v  = (const float*)d_in[2];
  const float* ig = (const float*)d_in[3];
  const float* fg = (const float*)d_in[4];

  const size_t gate_bytes = (size_t)3 * NBH * T_SEQ * sizeof(float);
  const size_t kv_elems   = (size_t)NBH * T_SEQ * DHEAD;
  const bool fast = ws_size >= gate_bytes + 2 * kv_elems * sizeof(u16);

  float* a_ws  = (float*)d_ws;
  float* c_ws  = a_ws + NBH * T_SEQ;
  float* fc_ws = c_ws + NBH * T_SEQ;
  u16* kbf  = (u16*)((char*)d_ws + gate_bytes);
  u16* vtbf = kbf + kv_elems;

  gate_scan_kernel<<<dim3(NBH), dim3(256), 0, stream>>>(ig, fg, a_ws, c_ws, fc_ws);
  if (fast) {
    cvt_k_kernel<<<dim3((unsigned)(kv_elems / 1024)), dim3(256), 0, stream>>>(
        k, a_ws, c_ws, kbf);
    cvt_vt_kernel<<<dim3(T_SEQ / 64, NBH), dim3(256), 0, stream>>>(v, vtbf);
    mlstm_fwd_kernel<true><<<dim3(256), dim3(512), 0, stream>>>(
        q, k, v, kbf, vtbf, a_ws, c_ws, fc_ws, (float*)d_out);
  } else {
    mlstm_fwd_kernel<false><<<dim3(256), dim3(512), 0, stream>>>(
        q, k, v, kbf, vtbf, a_ws, c_ws, fc_ws, (float*)d_out);
  }
}